// Round 12
// baseline (195.808 us; speedup 1.0000x reference)
//
#include <hip/hip_runtime.h>

#define H   128
#define P   32             // points per block
#define NT  512            // 8 waves: wave = jpair*2 + phalf

typedef _Float16 v8h __attribute__((ext_vector_type(8)));
typedef __fp16   h2  __attribute__((ext_vector_type(2)));   // cvt_pkrtz return type
typedef float    v4f __attribute__((ext_vector_type(4)));

union PK4 { h2 h[4]; uint4 u; };       // 8 f16 = 16 B

// State plane layout: [pl][p][k], 128 f16 per row, XOR-octet swizzle; returns
// f16 index of octet o of row p (row accesses b128-able, scatter ~4-way).
__device__ __forceinline__ int soct(int pl, int p, int o) {
    return ((pl * P + p) * 16 + (o ^ (p & 15))) << 3;
}

// Prepass (2nd dispatch is free: R10/R11 A-B showed the ~50us bench-kernel
// gap is fixed harness overhead, independent of dispatch count).
// Wt[l][j][k] = f16(W_l[k][j]); gather reads, coalesced b32 writes.
__global__ void wt_convert(const float* __restrict__ W1,
                           const float* __restrict__ W2,
                           _Float16* __restrict__ ws) {
    const int t = blockIdx.x * 64 + threadIdx.x;   // 0..16383
    const int l = t >> 13;
    const int r = t & 8191;
    const int j = r >> 6, kp = r & 63;
    const float* __restrict__ W = l ? W2 : W1;
    const float a = W[(2 * kp) * H + j];
    const float b = W[(2 * kp + 1) * H + j];
    union { h2 h; unsigned u; } q;
    q.h = __builtin_amdgcn_cvt_pkrtz(a, b);
    ((unsigned*)ws)[t] = q.u;
}

// Fast tanh + derivatives: v_exp + v_rcp (1 ulp) + fma. The naive 2/(e+1)
// compiles to the full IEEE divide sequence (~10 ops) without fast-math.
__device__ __forceinline__ void tanh_d2(float z, float& a, float& g1, float& g2) {
    const float e = __expf(2.f * z);                    // v_mul + v_exp_f32
    const float r = __builtin_amdgcn_rcpf(e + 1.f);     // v_add + v_rcp_f32
    a  = fmaf(-2.f, r, 1.f);                            // e=inf -> r=0 -> a=1; e=0 -> a=-1
    g1 = 1.f - a * a;
    g2 = -2.f * a * g1;
}

// Second-order forward-mode Hessian via f16 MFMA, z orientation (A = state
// from LDS, B = Wt from GLOBAL — L1/L2-resident, 4KB slice per wave).
// K-loop reads only stable LDS -> no internal barriers (4 total vs R10's 11);
// no sW buffer -> LDS 50.7KB -> 3 blocks/CU (24 waves).
// C layout (m89/m91): col j = l15, row p = quad*4+reg.
__global__ __launch_bounds__(NT, 6)
void pinn_hess_mfma(const float* __restrict__ X,
                    const float* __restrict__ W0, const float* __restrict__ b0,
                    const _Float16* __restrict__ Wt,
                    const float* __restrict__ b1, const float* __restrict__ b2,
                    const float* __restrict__ W3,
                    float* __restrict__ out, int N)
{
    __shared__ _Float16 sS[6 * P * H];        // 49152 B, swizzled state planes
    __shared__ float    sRed[3 * H];          // 1536 B, final-reduce scratch

    const int tid   = threadIdx.x;
    const int wave  = tid >> 6;               // 0..7
    const int phalf = wave & 1;               // p-half: rows phalf*16..+16
    const int jpair = wave >> 1;              // j-tile pair: cols jpair*32..+32
    const int lane  = tid & 63;
    const int quad  = lane >> 4;
    const int l15   = lane & 15;
    const int pbase = blockIdx.x * P;

    // ---------------- layer 0 (input dim 2, analytic); 512 tasks = 1/thread --
    {
        const int p = tid >> 4, o = tid & 15;
        const float x = X[2 * (pbase + p)];
        const float y = X[2 * (pbase + p) + 1];
        float wxv[8], wyv[8], bv[8];
        *(float4*)&wxv[0] = *(const float4*)&W0[o * 8];
        *(float4*)&wxv[4] = *(const float4*)&W0[o * 8 + 4];
        *(float4*)&wyv[0] = *(const float4*)&W0[H + o * 8];
        *(float4*)&wyv[4] = *(const float4*)&W0[H + o * 8 + 4];
        *(float4*)&bv[0]  = *(const float4*)&b0[o * 8];
        *(float4*)&bv[4]  = *(const float4*)&b0[o * 8 + 4];
        float r[6][8];
        #pragma unroll
        for (int u = 0; u < 8; ++u) {
            float a, g1, g2;
            tanh_d2(fmaf(x, wxv[u], fmaf(y, wyv[u], bv[u])), a, g1, g2);
            r[0][u] = a;
            r[1][u] = g1 * wxv[u];
            r[2][u] = g1 * wyv[u];
            r[3][u] = g2 * wxv[u] * wxv[u];
            r[4][u] = g2 * wxv[u] * wyv[u];
            r[5][u] = g2 * wyv[u] * wyv[u];
        }
        #pragma unroll
        for (int pl = 0; pl < 6; ++pl) {
            PK4 q;
            #pragma unroll
            for (int h = 0; h < 4; ++h)
                q.h[h] = __builtin_amdgcn_cvt_pkrtz(r[pl][2*h], r[pl][2*h+1]);
            *(uint4*)&sS[soct(pl, p, o)] = q.u;
        }
    }
    __syncthreads();                           // (1) state visible to all waves

    // ---------------- hidden layers ----------------
    for (int layer = 0; layer < 2; ++layer) {
        const _Float16* __restrict__ Wg = Wt + layer * H * H
                                        + (jpair * 32 + l15) * H + quad * 8;

        v4f C[6][2];
        #pragma unroll
        for (int pl = 0; pl < 6; ++pl) { C[pl][0] = (v4f){0,0,0,0}; C[pl][1] = (v4f){0,0,0,0}; }

        #pragma unroll
        for (int kc = 0; kc < 4; ++kc) {
            // B-frags from global (L1/L2-resident): rows j, j+16; k-octet of chunk
            const v8h B0 = *(const v8h*)&Wg[kc * 32];
            const v8h B1 = *(const v8h*)&Wg[16 * H + kc * 32];
            #pragma unroll
            for (int pl = 0; pl < 6; ++pl) {
                // A-frag: state plane pl, row p = phalf*16 + l15, octet kc*4+quad
                const v8h A = *(const v8h*)&sS[soct(pl, phalf * 16 + l15, kc * 4 + quad)];
                C[pl][0] = __builtin_amdgcn_mfma_f32_16x16x32_f16(A, B0, C[pl][0], 0, 0, 0);
                C[pl][1] = __builtin_amdgcn_mfma_f32_16x16x32_f16(A, B1, C[pl][1], 0, 0, 0);
            }
        }

        if (layer == 0) {
            __syncthreads();   // (2) all K-loop reads of old state done
            // in-register tanh chain rule; scatter new state (b16, ~4-way banks)
            #pragma unroll
            for (int nt = 0; nt < 2; ++nt) {
                const int j  = jpair * 32 + nt * 16 + l15;
                const int ob = j >> 3, wi = j & 7;
                const float bb = b1[j];
                #pragma unroll
                for (int r = 0; r < 4; ++r) {
                    const int p = phalf * 16 + quad * 4 + r;
                    float a, g1, g2;
                    tanh_d2(C[0][nt][r] + bb, a, g1, g2);
                    const float tx = C[1][nt][r], ty = C[2][nt][r];
                    sS[soct(0, p, ob) + wi] = (_Float16)a;
                    sS[soct(1, p, ob) + wi] = (_Float16)(g1 * tx);
                    sS[soct(2, p, ob) + wi] = (_Float16)(g1 * ty);
                    sS[soct(3, p, ob) + wi] = (_Float16)fmaf(g2 * tx, tx, g1 * C[3][nt][r]);
                    sS[soct(4, p, ob) + wi] = (_Float16)fmaf(g2 * tx, ty, g1 * C[4][nt][r]);
                    sS[soct(5, p, ob) + wi] = (_Float16)fmaf(g2 * ty, ty, g1 * C[5][nt][r]);
                }
            }
            __syncthreads();   // (3) new state visible for layer-2 K-loop
        } else {
            // final combine + W3 dot in registers; reduce j over l15 then jpair
            float hxx[4] = {0,0,0,0}, hxy[4] = {0,0,0,0}, hyy[4] = {0,0,0,0};
            #pragma unroll
            for (int nt = 0; nt < 2; ++nt) {
                const int j = jpair * 32 + nt * 16 + l15;
                const float bb = b2[j];
                const float w3 = W3[j];
                #pragma unroll
                for (int r = 0; r < 4; ++r) {
                    float a, g1, g2;
                    tanh_d2(C[0][nt][r] + bb, a, g1, g2);
                    const float tx = C[1][nt][r], ty = C[2][nt][r];
                    hxx[r] = fmaf(w3, fmaf(g2 * tx, tx, g1 * C[3][nt][r]), hxx[r]);
                    hxy[r] = fmaf(w3, fmaf(g2 * tx, ty, g1 * C[4][nt][r]), hxy[r]);
                    hyy[r] = fmaf(w3, fmaf(g2 * ty, ty, g1 * C[5][nt][r]), hyy[r]);
                }
            }
            #pragma unroll
            for (int off = 8; off > 0; off >>= 1)
                #pragma unroll
                for (int r = 0; r < 4; ++r) {
                    hxx[r] += __shfl_down(hxx[r], off, 16);
                    hxy[r] += __shfl_down(hxy[r], off, 16);
                    hyy[r] += __shfl_down(hyy[r], off, 16);
                }
            if (l15 == 0) {
                #pragma unroll
                for (int r = 0; r < 4; ++r) {
                    const int p = phalf * 16 + quad * 4 + r;
                    sRed[0 * 128 + jpair * 32 + p] = hxx[r];
                    sRed[1 * 128 + jpair * 32 + p] = hxy[r];
                    sRed[2 * 128 + jpair * 32 + p] = hyy[r];
                }
            }
            __syncthreads();   // (4) partials visible
            if (tid < 96) {
                const int c = tid >> 5, p = tid & 31;
                float acc = 0.f;
                #pragma unroll
                for (int jp = 0; jp < 4; ++jp)
                    acc += sRed[c * 128 + jp * 32 + p];
                out[c * N + pbase + p] = acc;
            }
        }
    }
}

extern "C" void kernel_launch(void* const* d_in, const int* in_sizes, int n_in,
                              void* d_out, int out_size, void* d_ws, size_t ws_size,
                              hipStream_t stream) {
    const float* X  = (const float*)d_in[0];
    const float* W0 = (const float*)d_in[1];
    const float* b0 = (const float*)d_in[2];
    const float* W1 = (const float*)d_in[3];
    const float* b1 = (const float*)d_in[4];
    const float* W2 = (const float*)d_in[5];
    const float* b2 = (const float*)d_in[6];
    const float* W3 = (const float*)d_in[7];
    // d_in[8] = b3: constant offset, zero second derivative -> unused.

    const int N = in_sizes[0] / 2;               // 131072 = 4096 * P
    float* out = (float*)d_out;
    _Float16* ws = (_Float16*)d_ws;              // Wt[2][128][128] f16 = 64 KB

    hipLaunchKernelGGL(wt_convert, dim3(256), dim3(64), 0, stream, W1, W2, ws);

    hipLaunchKernelGGL(pinn_hess_mfma, dim3(N / P), dim3(NT), 0, stream,
                       X, W0, b0, ws, b1, b2, W3, out, N);
}

// Round 13
// 169.202 us; speedup vs baseline: 1.1572x; 1.1572x over previous
//
#include <hip/hip_runtime.h>

#define H   128
#define P   32             // points per block
#define NT  512            // 8 waves: wave = jpair*2 + phalf

typedef _Float16 v8h __attribute__((ext_vector_type(8)));
typedef __fp16   h2  __attribute__((ext_vector_type(2)));   // cvt_pkrtz return type
typedef float    v4f __attribute__((ext_vector_type(4)));

union PK4 { h2 h[4]; uint4 u; };       // 8 f16 = 16 B

// State plane layout: [pl][p][k], 128 f16 per row, XOR-octet swizzle; returns
// f16 index of octet o of row p (row accesses b128-able, scatter ~4-way).
__device__ __forceinline__ int soct(int pl, int p, int o) {
    return ((pl * P + p) * 16 + (o ^ (p & 15))) << 3;
}

// Prepass (2nd dispatch is free: R10/R11 A-B showed the ~50us bench-kernel
// gap is fixed harness overhead, independent of dispatch count).
// Wt[l][j][k] = f16(W_l[k][j]); gather reads, coalesced b32 writes.
__global__ void wt_convert(const float* __restrict__ W1,
                           const float* __restrict__ W2,
                           _Float16* __restrict__ ws) {
    const int t = blockIdx.x * 64 + threadIdx.x;   // 0..16383
    const int l = t >> 13;
    const int r = t & 8191;
    const int j = r >> 6, kp = r & 63;
    const float* __restrict__ W = l ? W2 : W1;
    const float a = W[(2 * kp) * H + j];
    const float b = W[(2 * kp + 1) * H + j];
    union { h2 h; unsigned u; } q;
    q.h = __builtin_amdgcn_cvt_pkrtz(a, b);
    ((unsigned*)ws)[t] = q.u;
}

// Fast tanh + derivatives: v_exp + v_rcp (1 ulp) + fma.
__device__ __forceinline__ void tanh_d2(float z, float& a, float& g1, float& g2) {
    const float e = __expf(2.f * z);                    // v_mul + v_exp_f32
    const float r = __builtin_amdgcn_rcpf(e + 1.f);     // v_add + v_rcp_f32
    a  = fmaf(-2.f, r, 1.f);                            // e=inf -> r=0 -> a=1
    g1 = 1.f - a * a;
    g2 = -2.f * a * g1;
}

// Second-order forward-mode Hessian via f16 MFMA, z orientation (A = state
// from LDS, B = Wt from GLOBAL — L1/L2-resident, 4KB slice per wave).
// K-loop reads only stable LDS -> 4 barriers/block total.
// R12 post-mortem: __launch_bounds__(512,6) capped unified VGPR+AGPR at ~85 <
// the ~100-reg footprint (48 acc + frags + temps) -> 211MB scratch spill.
// (512,4) = 128-reg cap is R10-proven spill-free for this exact footprint;
// occupancy 2 blocks/CU (register-capped), which R10 showed is sufficient.
__global__ __launch_bounds__(NT, 4)
void pinn_hess_mfma(const float* __restrict__ X,
                    const float* __restrict__ W0, const float* __restrict__ b0,
                    const _Float16* __restrict__ Wt,
                    const float* __restrict__ b1, const float* __restrict__ b2,
                    const float* __restrict__ W3,
                    float* __restrict__ out, int N)
{
    __shared__ _Float16 sS[6 * P * H];        // 49152 B, swizzled state planes
    __shared__ float    sRed[3 * H];          // 1536 B, final-reduce scratch

    const int tid   = threadIdx.x;
    const int wave  = tid >> 6;               // 0..7
    const int phalf = wave & 1;               // p-half: rows phalf*16..+16
    const int jpair = wave >> 1;              // j-tile pair: cols jpair*32..+32
    const int lane  = tid & 63;
    const int quad  = lane >> 4;
    const int l15   = lane & 15;
    const int pbase = blockIdx.x * P;

    // ---------------- layer 0 (input dim 2, analytic); 512 tasks = 1/thread --
    {
        const int p = tid >> 4, o = tid & 15;
        const float x = X[2 * (pbase + p)];
        const float y = X[2 * (pbase + p) + 1];
        float wxv[8], wyv[8], bv[8];
        *(float4*)&wxv[0] = *(const float4*)&W0[o * 8];
        *(float4*)&wxv[4] = *(const float4*)&W0[o * 8 + 4];
        *(float4*)&wyv[0] = *(const float4*)&W0[H + o * 8];
        *(float4*)&wyv[4] = *(const float4*)&W0[H + o * 8 + 4];
        *(float4*)&bv[0]  = *(const float4*)&b0[o * 8];
        *(float4*)&bv[4]  = *(const float4*)&b0[o * 8 + 4];
        float r[6][8];
        #pragma unroll
        for (int u = 0; u < 8; ++u) {
            float a, g1, g2;
            tanh_d2(fmaf(x, wxv[u], fmaf(y, wyv[u], bv[u])), a, g1, g2);
            r[0][u] = a;
            r[1][u] = g1 * wxv[u];
            r[2][u] = g1 * wyv[u];
            r[3][u] = g2 * wxv[u] * wxv[u];
            r[4][u] = g2 * wxv[u] * wyv[u];
            r[5][u] = g2 * wyv[u] * wyv[u];
        }
        #pragma unroll
        for (int pl = 0; pl < 6; ++pl) {
            PK4 q;
            #pragma unroll
            for (int h = 0; h < 4; ++h)
                q.h[h] = __builtin_amdgcn_cvt_pkrtz(r[pl][2*h], r[pl][2*h+1]);
            *(uint4*)&sS[soct(pl, p, o)] = q.u;
        }
    }
    __syncthreads();                           // (1) state visible to all waves

    // ---------------- hidden layers ----------------
    for (int layer = 0; layer < 2; ++layer) {
        const _Float16* __restrict__ Wg = Wt + layer * H * H
                                        + (jpair * 32 + l15) * H + quad * 8;

        v4f C[6][2];
        #pragma unroll
        for (int pl = 0; pl < 6; ++pl) { C[pl][0] = (v4f){0,0,0,0}; C[pl][1] = (v4f){0,0,0,0}; }

        #pragma unroll
        for (int kc = 0; kc < 4; ++kc) {
            // B-frags from global (L1/L2-resident): rows j, j+16; k-octet of chunk
            const v8h B0 = *(const v8h*)&Wg[kc * 32];
            const v8h B1 = *(const v8h*)&Wg[16 * H + kc * 32];
            #pragma unroll
            for (int pl = 0; pl < 6; ++pl) {
                // A-frag: state plane pl, row p = phalf*16 + l15, octet kc*4+quad
                const v8h A = *(const v8h*)&sS[soct(pl, phalf * 16 + l15, kc * 4 + quad)];
                C[pl][0] = __builtin_amdgcn_mfma_f32_16x16x32_f16(A, B0, C[pl][0], 0, 0, 0);
                C[pl][1] = __builtin_amdgcn_mfma_f32_16x16x32_f16(A, B1, C[pl][1], 0, 0, 0);
            }
        }

        if (layer == 0) {
            __syncthreads();   // (2) all K-loop reads of old state done
            // in-register tanh chain rule; scatter new state (b16, ~4-way banks)
            #pragma unroll
            for (int nt = 0; nt < 2; ++nt) {
                const int j  = jpair * 32 + nt * 16 + l15;
                const int ob = j >> 3, wi = j & 7;
                const float bb = b1[j];
                #pragma unroll
                for (int r = 0; r < 4; ++r) {
                    const int p = phalf * 16 + quad * 4 + r;
                    float a, g1, g2;
                    tanh_d2(C[0][nt][r] + bb, a, g1, g2);
                    const float tx = C[1][nt][r], ty = C[2][nt][r];
                    sS[soct(0, p, ob) + wi] = (_Float16)a;
                    sS[soct(1, p, ob) + wi] = (_Float16)(g1 * tx);
                    sS[soct(2, p, ob) + wi] = (_Float16)(g1 * ty);
                    sS[soct(3, p, ob) + wi] = (_Float16)fmaf(g2 * tx, tx, g1 * C[3][nt][r]);
                    sS[soct(4, p, ob) + wi] = (_Float16)fmaf(g2 * tx, ty, g1 * C[4][nt][r]);
                    sS[soct(5, p, ob) + wi] = (_Float16)fmaf(g2 * ty, ty, g1 * C[5][nt][r]);
                }
            }
            __syncthreads();   // (3) new state visible for layer-2 K-loop
        } else {
            // final combine + W3 dot in registers; reduce j over l15 then jpair
            float hxx[4] = {0,0,0,0}, hxy[4] = {0,0,0,0}, hyy[4] = {0,0,0,0};
            #pragma unroll
            for (int nt = 0; nt < 2; ++nt) {
                const int j = jpair * 32 + nt * 16 + l15;
                const float bb = b2[j];
                const float w3 = W3[j];
                #pragma unroll
                for (int r = 0; r < 4; ++r) {
                    float a, g1, g2;
                    tanh_d2(C[0][nt][r] + bb, a, g1, g2);
                    const float tx = C[1][nt][r], ty = C[2][nt][r];
                    hxx[r] = fmaf(w3, fmaf(g2 * tx, tx, g1 * C[3][nt][r]), hxx[r]);
                    hxy[r] = fmaf(w3, fmaf(g2 * tx, ty, g1 * C[4][nt][r]), hxy[r]);
                    hyy[r] = fmaf(w3, fmaf(g2 * ty, ty, g1 * C[5][nt][r]), hyy[r]);
                }
            }
            #pragma unroll
            for (int off = 8; off > 0; off >>= 1)
                #pragma unroll
                for (int r = 0; r < 4; ++r) {
                    hxx[r] += __shfl_down(hxx[r], off, 16);
                    hxy[r] += __shfl_down(hxy[r], off, 16);
                    hyy[r] += __shfl_down(hyy[r], off, 16);
                }
            if (l15 == 0) {
                #pragma unroll
                for (int r = 0; r < 4; ++r) {
                    const int p = phalf * 16 + quad * 4 + r;
                    sRed[0 * 128 + jpair * 32 + p] = hxx[r];
                    sRed[1 * 128 + jpair * 32 + p] = hxy[r];
                    sRed[2 * 128 + jpair * 32 + p] = hyy[r];
                }
            }
            __syncthreads();   // (4) partials visible
            if (tid < 96) {
                const int c = tid >> 5, p = tid & 31;
                float acc = 0.f;
                #pragma unroll
                for (int jp = 0; jp < 4; ++jp)
                    acc += sRed[c * 128 + jp * 32 + p];
                out[c * N + pbase + p] = acc;
            }
        }
    }
}

extern "C" void kernel_launch(void* const* d_in, const int* in_sizes, int n_in,
                              void* d_out, int out_size, void* d_ws, size_t ws_size,
                              hipStream_t stream) {
    const float* X  = (const float*)d_in[0];
    const float* W0 = (const float*)d_in[1];
    const float* b0 = (const float*)d_in[2];
    const float* W1 = (const float*)d_in[3];
    const float* b1 = (const float*)d_in[4];
    const float* W2 = (const float*)d_in[5];
    const float* b2 = (const float*)d_in[6];
    const float* W3 = (const float*)d_in[7];
    // d_in[8] = b3: constant offset, zero second derivative -> unused.

    const int N = in_sizes[0] / 2;               // 131072 = 4096 * P
    float* out = (float*)d_out;
    _Float16* ws = (_Float16*)d_ws;              // Wt[2][128][128] f16 = 64 KB

    hipLaunchKernelGGL(wt_convert, dim3(256), dim3(64), 0, stream, W1, W2, ws);

    hipLaunchKernelGGL(pinn_hess_mfma, dim3(N / P), dim3(NT), 0, stream,
                       X, W0, b0, ws, b1, b2, W3, out, N);
}

// Round 14
// 145.522 us; speedup vs baseline: 1.3456x; 1.1627x over previous
//
#include <hip/hip_runtime.h>

#define H   128
#define P   32             // points per block
#define NT  512            // 8 waves: wave = jpair*2 + phalf

typedef _Float16 v8h __attribute__((ext_vector_type(8)));
typedef __fp16   h2  __attribute__((ext_vector_type(2)));   // cvt_pkrtz return type
typedef float    v4f __attribute__((ext_vector_type(4)));

union PK4 { h2 h[4]; uint4 u; };       // 8 f16 = 16 B

// State plane layout: [pl][p][k], 128 f16 per row, XOR-octet swizzle; returns
// f16 index of octet o of row p (row accesses b128-able, scatter ~4-way).
__device__ __forceinline__ int soct(int pl, int p, int o) {
    return ((pl * P + p) * 16 + (o ^ (p & 15))) << 3;
}

// Prepass (2nd dispatch is free — R10/R11 A/B): writes Wt in the MAIN KERNEL'S
// LDS PHYSICAL ORDER: ws[l][oct][j][8] where oct = k>>3 (16 octet-planes of
// 128 j-rows each). Main-kernel staging becomes a linear memcpy, and B-frag
// reads (16 consecutive j at fixed oct) hit banks (j*4)%32 -> full 32-bank
// spread, 2-way aliasing = free (m136).
__global__ void wt_convert(const float* __restrict__ W1,
                           const float* __restrict__ W2,
                           _Float16* __restrict__ ws) {
    const int t = blockIdx.x * 64 + threadIdx.x;   // 0..16383 (u32 units)
    const int l = t >> 13;
    const int r = t & 8191;                        // u32 within layer
    const int oct = r >> 9;                        // k-octet 0..15
    const int rem = r & 511;
    const int j  = rem >> 2;                       // 0..127
    const int wp = rem & 3;                        // half-pair within octet
    const int k  = oct * 8 + 2 * wp;
    const float* __restrict__ W = l ? W2 : W1;
    const float a = W[k * H + j];
    const float b = W[(k + 1) * H + j];
    union { h2 h; unsigned u; } q;
    q.h = __builtin_amdgcn_cvt_pkrtz(a, b);
    ((unsigned*)ws)[t] = q.u;                      // coalesced b32 writes
}

// Fast tanh + derivatives: v_exp + v_rcp (1 ulp) + fma.
__device__ __forceinline__ void tanh_d2(float z, float& a, float& g1, float& g2) {
    const float e = __expf(2.f * z);
    const float r = __builtin_amdgcn_rcpf(e + 1.f);
    a  = fmaf(-2.f, r, 1.f);                       // e=inf -> r=0 -> a=1
    g1 = 1.f - a * a;
    g2 = -2.f * a * g1;
}

// Second-order forward-mode Hessian via f16 MFMA, z orientation (A = state
// from LDS, B = Wt from LDS, whole 32KB layer staged ONCE per layer via
// linear memcpy of the pre-swizzled prepass output).
// R13 post-mortem: global-B in the K-loop = 200+cyc L2 chains, unhidden at
// 16 waves/CU -> both pipes <42%. LDS-B restores R10's latency behavior
// without its 11 barriers (5 here) or staging VALU (pure memcpy).
// LDS: 49152 (state) + 32768 (W layer) = 81920 B exactly -> 2 blocks/CU.
__global__ __launch_bounds__(NT, 4)
void pinn_hess_mfma(const float* __restrict__ X,
                    const float* __restrict__ W0, const float* __restrict__ b0,
                    const _Float16* __restrict__ Wt,
                    const float* __restrict__ b1, const float* __restrict__ b2,
                    const float* __restrict__ W3,
                    float* __restrict__ out, int N)
{
    __shared__ _Float16 sS[6 * P * H];        // 49152 B, swizzled state planes
    __shared__ _Float16 sW[16 * H * 8];       // 32768 B, one full W layer (oct-planes)

    const int tid   = threadIdx.x;
    const int wave  = tid >> 6;               // 0..7
    const int phalf = wave & 1;               // p-half: rows phalf*16..+16
    const int jpair = wave >> 1;              // j-tile pair: cols jpair*32..+32
    const int lane  = tid & 63;
    const int quad  = lane >> 4;
    const int l15   = lane & 15;
    const int pbase = blockIdx.x * P;

    // ---------------- layer 0 (input dim 2, analytic); 512 tasks = 1/thread --
    {
        const int p = tid >> 4, o = tid & 15;
        const float x = X[2 * (pbase + p)];
        const float y = X[2 * (pbase + p) + 1];
        float wxv[8], wyv[8], bv[8];
        *(float4*)&wxv[0] = *(const float4*)&W0[o * 8];
        *(float4*)&wxv[4] = *(const float4*)&W0[o * 8 + 4];
        *(float4*)&wyv[0] = *(const float4*)&W0[H + o * 8];
        *(float4*)&wyv[4] = *(const float4*)&W0[H + o * 8 + 4];
        *(float4*)&bv[0]  = *(const float4*)&b0[o * 8];
        *(float4*)&bv[4]  = *(const float4*)&b0[o * 8 + 4];
        float r[6][8];
        #pragma unroll
        for (int u = 0; u < 8; ++u) {
            float a, g1, g2;
            tanh_d2(fmaf(x, wxv[u], fmaf(y, wyv[u], bv[u])), a, g1, g2);
            r[0][u] = a;
            r[1][u] = g1 * wxv[u];
            r[2][u] = g1 * wyv[u];
            r[3][u] = g2 * wxv[u] * wxv[u];
            r[4][u] = g2 * wxv[u] * wyv[u];
            r[5][u] = g2 * wyv[u] * wyv[u];
        }
        #pragma unroll
        for (int pl = 0; pl < 6; ++pl) {
            PK4 q;
            #pragma unroll
            for (int h = 0; h < 4; ++h)
                q.h[h] = __builtin_amdgcn_cvt_pkrtz(r[pl][2*h], r[pl][2*h+1]);
            *(uint4*)&sS[soct(pl, p, o)] = q.u;
        }
    }

    // ---------------- hidden layers ----------------
    for (int layer = 0; layer < 2; ++layer) {
        // stage whole layer: linear memcpy, 4 b128 per thread, both sides coalesced
        {
            const v8h* src = (const v8h*)(Wt + layer * 16 * H * 8);
            v8h*       dst = (v8h*)sW;
            #pragma unroll
            for (int i = 0; i < 4; ++i)
                dst[tid + i * NT] = src[tid + i * NT];
        }
        __syncthreads();   // (1)/(3): sW + sS writes visible

        v4f C[6][2];
        #pragma unroll
        for (int pl = 0; pl < 6; ++pl) { C[pl][0] = (v4f){0,0,0,0}; C[pl][1] = (v4f){0,0,0,0}; }

        #pragma unroll
        for (int kc = 0; kc < 4; ++kc) {
            // B-frags: oct-plane kc*4+quad, rows j / j+16 (2-way banks = free)
            const v8h B0 = *(const v8h*)&sW[(((kc * 4 + quad) * H) + jpair * 32 + l15)      * 8];
            const v8h B1 = *(const v8h*)&sW[(((kc * 4 + quad) * H) + jpair * 32 + 16 + l15) * 8];
            #pragma unroll
            for (int pl = 0; pl < 6; ++pl) {
                // A-frag: state plane pl, row p = phalf*16 + l15, octet kc*4+quad
                const v8h A = *(const v8h*)&sS[soct(pl, phalf * 16 + l15, kc * 4 + quad)];
                C[pl][0] = __builtin_amdgcn_mfma_f32_16x16x32_f16(A, B0, C[pl][0], 0, 0, 0);
                C[pl][1] = __builtin_amdgcn_mfma_f32_16x16x32_f16(A, B1, C[pl][1], 0, 0, 0);
            }
        }
        __syncthreads();   // (2)/(4): all K-loop reads of sS + sW done

        if (layer == 0) {
            // in-register tanh chain rule; scatter new state (b16, ~4-way banks)
            // (next iteration's stage writes sW - disjoint from sS - then barrier)
            #pragma unroll
            for (int nt = 0; nt < 2; ++nt) {
                const int j  = jpair * 32 + nt * 16 + l15;
                const int ob = j >> 3, wi = j & 7;
                const float bb = b1[j];
                #pragma unroll
                for (int r = 0; r < 4; ++r) {
                    const int p = phalf * 16 + quad * 4 + r;
                    float a, g1, g2;
                    tanh_d2(C[0][nt][r] + bb, a, g1, g2);
                    const float tx = C[1][nt][r], ty = C[2][nt][r];
                    sS[soct(0, p, ob) + wi] = (_Float16)a;
                    sS[soct(1, p, ob) + wi] = (_Float16)(g1 * tx);
                    sS[soct(2, p, ob) + wi] = (_Float16)(g1 * ty);
                    sS[soct(3, p, ob) + wi] = (_Float16)fmaf(g2 * tx, tx, g1 * C[3][nt][r]);
                    sS[soct(4, p, ob) + wi] = (_Float16)fmaf(g2 * tx, ty, g1 * C[4][nt][r]);
                    sS[soct(5, p, ob) + wi] = (_Float16)fmaf(g2 * ty, ty, g1 * C[5][nt][r]);
                }
            }
        } else {
            // final combine + W3 dot in registers; reduce j over l15 then jpair
            float hxx[4] = {0,0,0,0}, hxy[4] = {0,0,0,0}, hyy[4] = {0,0,0,0};
            #pragma unroll
            for (int nt = 0; nt < 2; ++nt) {
                const int j = jpair * 32 + nt * 16 + l15;
                const float bb = b2[j];
                const float w3 = W3[j];
                #pragma unroll
                for (int r = 0; r < 4; ++r) {
                    float a, g1, g2;
                    tanh_d2(C[0][nt][r] + bb, a, g1, g2);
                    const float tx = C[1][nt][r], ty = C[2][nt][r];
                    hxx[r] = fmaf(w3, fmaf(g2 * tx, tx, g1 * C[3][nt][r]), hxx[r]);
                    hxy[r] = fmaf(w3, fmaf(g2 * tx, ty, g1 * C[4][nt][r]), hxy[r]);
                    hyy[r] = fmaf(w3, fmaf(g2 * ty, ty, g1 * C[5][nt][r]), hyy[r]);
                }
            }
            #pragma unroll
            for (int off = 8; off > 0; off >>= 1)
                #pragma unroll
                for (int r = 0; r < 4; ++r) {
                    hxx[r] += __shfl_down(hxx[r], off, 16);
                    hxy[r] += __shfl_down(hxy[r], off, 16);
                    hyy[r] += __shfl_down(hyy[r], off, 16);
                }
            // sW free after barrier (4): reuse as reduce scratch
            float* sRed = (float*)sW;
            if (l15 == 0) {
                #pragma unroll
                for (int r = 0; r < 4; ++r) {
                    const int p = phalf * 16 + quad * 4 + r;
                    sRed[0 * 128 + jpair * 32 + p] = hxx[r];
                    sRed[1 * 128 + jpair * 32 + p] = hxy[r];
                    sRed[2 * 128 + jpair * 32 + p] = hyy[r];
                }
            }
            __syncthreads();   // (5) partials visible
            if (tid < 96) {
                const int c = tid >> 5, p = tid & 31;
                float acc = 0.f;
                #pragma unroll
                for (int jp = 0; jp < 4; ++jp)
                    acc += sRed[c * 128 + jp * 32 + p];
                out[c * N + pbase + p] = acc;
            }
        }
    }
}

extern "C" void kernel_launch(void* const* d_in, const int* in_sizes, int n_in,
                              void* d_out, int out_size, void* d_ws, size_t ws_size,
                              hipStream_t stream) {
    const float* X  = (const float*)d_in[0];
    const float* W0 = (const float*)d_in[1];
    const float* b0 = (const float*)d_in[2];
    const float* W1 = (const float*)d_in[3];
    const float* b1 = (const float*)d_in[4];
    const float* W2 = (const float*)d_in[5];
    const float* b2 = (const float*)d_in[6];
    const float* W3 = (const float*)d_in[7];
    // d_in[8] = b3: constant offset, zero second derivative -> unused.

    const int N = in_sizes[0] / 2;               // 131072 = 4096 * P
    float* out = (float*)d_out;
    _Float16* ws = (_Float16*)d_ws;              // Wt[2][16][128][8] f16 = 64 KB

    hipLaunchKernelGGL(wt_convert, dim3(256), dim3(64), 0, stream, W1, W2, ws);

    hipLaunchKernelGGL(pinn_hess_mfma, dim3(N / P), dim3(NT), 0, stream,
                       X, W0, b0, ws, b1, b2, W3, out, N);
}

// Round 15
// 132.936 us; speedup vs baseline: 1.4730x; 1.0947x over previous
//
#include <hip/hip_runtime.h>

#define H   128
#define P   32             // points per block
#define NT  512            // 8 waves: wave = jquad*2 + phalf

typedef _Float16 v8h __attribute__((ext_vector_type(8)));
typedef __fp16   h2  __attribute__((ext_vector_type(2)));   // cvt_pkrtz return type
typedef float    v4f __attribute__((ext_vector_type(4)));

union PK4 { h2 h[4]; uint4 u; };       // 8 f16 = 16 B
union PK2 { h2 h[2]; uint2 u; };       // 4 f16 = 8 B

// State plane layout: [pl][p][k], 128 f16 per row, XOR-octet swizzle; returns
// f16 index of octet o of row p.
__device__ __forceinline__ int soct(int pl, int p, int o) {
    return ((pl * P + p) * 16 + (o ^ (p & 15))) << 3;
}

// Prepass (2nd dispatch is free — R10/R11 A/B): Wt in LDS physical order
// ws[l][oct][j][8], oct = k>>3. Main-kernel staging = pure linear memcpy.
__global__ void wt_convert(const float* __restrict__ W1,
                           const float* __restrict__ W2,
                           _Float16* __restrict__ ws) {
    const int t = blockIdx.x * 64 + threadIdx.x;   // 0..16383 (u32 units)
    const int l = t >> 13;
    const int r = t & 8191;
    const int oct = r >> 9;
    const int rem = r & 511;
    const int j  = rem >> 2;
    const int wp = rem & 3;
    const int k  = oct * 8 + 2 * wp;
    const float* __restrict__ W = l ? W2 : W1;
    const float a = W[k * H + j];
    const float b = W[(k + 1) * H + j];
    union { h2 h; unsigned u; } q;
    q.h = __builtin_amdgcn_cvt_pkrtz(a, b);
    ((unsigned*)ws)[t] = q.u;
}

// Fast tanh + derivatives: v_exp + v_rcp (1 ulp) + fma.
__device__ __forceinline__ void tanh_d2(float z, float& a, float& g1, float& g2) {
    const float e = __expf(2.f * z);
    const float r = __builtin_amdgcn_rcpf(e + 1.f);
    a  = fmaf(-2.f, r, 1.f);                       // e=inf -> r=0 -> a=1
    g1 = 1.f - a * a;
    g2 = -2.f * a * g1;
}

// R15: GEMM orientation swapped vs R14 — A = Wt (m=j), B = state (n=p), so
// C gives each lane 4 CONSECUTIVE j at fixed p (state-row order):
//   combine: 12 b64 stores + 24 pkrtz   (was 48 b16 scatter + 48 cvt)
//   final:   6 shfl_xor (quad butterfly) (was 48 shuffles + 48 adds)
// GEMM cost unchanged (reads swap roles; 8 b128/kc, 48 MFMA/wave, 48 acc).
// C layout (m89/m91): row j = quad*4+r, col p = l15.
__global__ __launch_bounds__(NT, 4)
void pinn_hess_mfma(const float* __restrict__ X,
                    const float* __restrict__ W0, const float* __restrict__ b0,
                    const _Float16* __restrict__ Wt,
                    const float* __restrict__ b1, const float* __restrict__ b2,
                    const float* __restrict__ W3,
                    float* __restrict__ out, int N)
{
    __shared__ _Float16 sS[6 * P * H];        // 49152 B, swizzled state planes
    __shared__ _Float16 sW[16 * H * 8];       // 32768 B, one full W layer (oct-planes)

    const int tid   = threadIdx.x;
    const int wave  = tid >> 6;               // 0..7
    const int phalf = wave & 1;               // p-half: cols phalf*16..+16
    const int jquad = wave >> 1;              // j range jquad*32..+32
    const int lane  = tid & 63;
    const int quad  = lane >> 4;
    const int l15   = lane & 15;
    const int pbase = blockIdx.x * P;
    const int pmy   = phalf * 16 + l15;       // this lane's point row (GEMM n)

    // ---------------- layer 0 (input dim 2, analytic); 512 tasks = 1/thread --
    {
        const int p = tid >> 4, o = tid & 15;
        const float x = X[2 * (pbase + p)];
        const float y = X[2 * (pbase + p) + 1];
        float wxv[8], wyv[8], bv[8];
        *(float4*)&wxv[0] = *(const float4*)&W0[o * 8];
        *(float4*)&wxv[4] = *(const float4*)&W0[o * 8 + 4];
        *(float4*)&wyv[0] = *(const float4*)&W0[H + o * 8];
        *(float4*)&wyv[4] = *(const float4*)&W0[H + o * 8 + 4];
        *(float4*)&bv[0]  = *(const float4*)&b0[o * 8];
        *(float4*)&bv[4]  = *(const float4*)&b0[o * 8 + 4];
        float r[6][8];
        #pragma unroll
        for (int u = 0; u < 8; ++u) {
            float a, g1, g2;
            tanh_d2(fmaf(x, wxv[u], fmaf(y, wyv[u], bv[u])), a, g1, g2);
            r[0][u] = a;
            r[1][u] = g1 * wxv[u];
            r[2][u] = g1 * wyv[u];
            r[3][u] = g2 * wxv[u] * wxv[u];
            r[4][u] = g2 * wxv[u] * wyv[u];
            r[5][u] = g2 * wyv[u] * wyv[u];
        }
        #pragma unroll
        for (int pl = 0; pl < 6; ++pl) {
            PK4 q;
            #pragma unroll
            for (int h = 0; h < 4; ++h)
                q.h[h] = __builtin_amdgcn_cvt_pkrtz(r[pl][2*h], r[pl][2*h+1]);
            *(uint4*)&sS[soct(pl, p, o)] = q.u;
        }
    }

    // ---------------- hidden layers ----------------
    for (int layer = 0; layer < 2; ++layer) {
        // stage whole layer: linear memcpy, 4 b128 per thread, both sides coalesced
        {
            const v8h* src = (const v8h*)(Wt + layer * 16 * H * 8);
            v8h*       dst = (v8h*)sW;
            #pragma unroll
            for (int i = 0; i < 4; ++i)
                dst[tid + i * NT] = src[tid + i * NT];
        }
        __syncthreads();   // (1)/(3): sW + sS writes visible

        v4f C[6][2];
        #pragma unroll
        for (int pl = 0; pl < 6; ++pl) { C[pl][0] = (v4f){0,0,0,0}; C[pl][1] = (v4f){0,0,0,0}; }

        #pragma unroll
        for (int kc = 0; kc < 4; ++kc) {
            const int oct = kc * 4 + quad;
            // A-frags: Wt rows j = jquad*32 + mt*16 + l15 at oct-plane (2-way banks)
            const v8h A0 = *(const v8h*)&sW[(oct * H + jquad * 32 + l15)      * 8];
            const v8h A1 = *(const v8h*)&sW[(oct * H + jquad * 32 + 16 + l15) * 8];
            #pragma unroll
            for (int pl = 0; pl < 6; ++pl) {
                // B-frag: state plane pl, row p = pmy, octet oct
                const v8h B = *(const v8h*)&sS[soct(pl, pmy, oct)];
                C[pl][0] = __builtin_amdgcn_mfma_f32_16x16x32_f16(A0, B, C[pl][0], 0, 0, 0);
                C[pl][1] = __builtin_amdgcn_mfma_f32_16x16x32_f16(A1, B, C[pl][1], 0, 0, 0);
            }
        }
        __syncthreads();   // (2)/(4): all K-loop reads of sS + sW done

        if (layer == 0) {
            // in-register tanh chain rule; VECTOR writeback: 4 consecutive j
            // per lane at row pmy -> one b64 per plane per tile
            #pragma unroll
            for (int mt = 0; mt < 2; ++mt) {
                const int j0 = jquad * 32 + mt * 16 + quad * 4;
                const float4 bv = *(const float4*)&b1[j0];
                float s[6][4];
                #pragma unroll
                for (int r = 0; r < 4; ++r) {
                    float a, g1, g2;
                    tanh_d2(C[0][mt][r] + ((const float*)&bv)[r], a, g1, g2);
                    const float tx = C[1][mt][r], ty = C[2][mt][r];
                    s[0][r] = a;
                    s[1][r] = g1 * tx;
                    s[2][r] = g1 * ty;
                    s[3][r] = fmaf(g2 * tx, tx, g1 * C[3][mt][r]);
                    s[4][r] = fmaf(g2 * tx, ty, g1 * C[4][mt][r]);
                    s[5][r] = fmaf(g2 * ty, ty, g1 * C[5][mt][r]);
                }
                const int ob = j0 >> 3;            // octet of j0
                const int ho = (quad & 1) * 4;     // half-offset within octet
                #pragma unroll
                for (int pl = 0; pl < 6; ++pl) {
                    PK2 q;
                    q.h[0] = __builtin_amdgcn_cvt_pkrtz(s[pl][0], s[pl][1]);
                    q.h[1] = __builtin_amdgcn_cvt_pkrtz(s[pl][2], s[pl][3]);
                    *(uint2*)&sS[soct(pl, pmy, ob) + ho] = q.u;
                }
            }
        } else {
            // final combine + W3 dot: lane accumulates its 8 j at its own p
            float oxx = 0.f, oxy = 0.f, oyy = 0.f;
            #pragma unroll
            for (int mt = 0; mt < 2; ++mt) {
                const int j0 = jquad * 32 + mt * 16 + quad * 4;
                const float4 bv = *(const float4*)&b2[j0];
                const float4 wv = *(const float4*)&W3[j0];
                #pragma unroll
                for (int r = 0; r < 4; ++r) {
                    float a, g1, g2;
                    tanh_d2(C[0][mt][r] + ((const float*)&bv)[r], a, g1, g2);
                    const float tx = C[1][mt][r], ty = C[2][mt][r];
                    const float w3 = ((const float*)&wv)[r];
                    oxx = fmaf(w3, fmaf(g2 * tx, tx, g1 * C[3][mt][r]), oxx);
                    oxy = fmaf(w3, fmaf(g2 * tx, ty, g1 * C[4][mt][r]), oxy);
                    oyy = fmaf(w3, fmaf(g2 * ty, ty, g1 * C[5][mt][r]), oyy);
                }
            }
            // reduce over quads (same p, disjoint j): 2-step butterfly
            oxx += __shfl_xor(oxx, 16); oxx += __shfl_xor(oxx, 32);
            oxy += __shfl_xor(oxy, 16); oxy += __shfl_xor(oxy, 32);
            oyy += __shfl_xor(oyy, 16); oyy += __shfl_xor(oyy, 32);
            // cross-wave (jquad) partials via sW-reuse (free after barrier 4)
            float* sRed = (float*)sW;              // [3][4 jquad][32 p]
            if (quad == 0) {
                sRed[0 * 128 + jquad * 32 + pmy] = oxx;
                sRed[1 * 128 + jquad * 32 + pmy] = oxy;
                sRed[2 * 128 + jquad * 32 + pmy] = oyy;
            }
            __syncthreads();   // (5) partials visible
            if (tid < 96) {
                const int c = tid >> 5, p = tid & 31;
                float acc = 0.f;
                #pragma unroll
                for (int jq = 0; jq < 4; ++jq)
                    acc += sRed[c * 128 + jq * 32 + p];
                out[c * N + pbase + p] = acc;
            }
        }
    }
}

extern "C" void kernel_launch(void* const* d_in, const int* in_sizes, int n_in,
                              void* d_out, int out_size, void* d_ws, size_t ws_size,
                              hipStream_t stream) {
    const float* X  = (const float*)d_in[0];
    const float* W0 = (const float*)d_in[1];
    const float* b0 = (const float*)d_in[2];
    const float* W1 = (const float*)d_in[3];
    const float* b1 = (const float*)d_in[4];
    const float* W2 = (const float*)d_in[5];
    const float* b2 = (const float*)d_in[6];
    const float* W3 = (const float*)d_in[7];
    // d_in[8] = b3: constant offset, zero second derivative -> unused.

    const int N = in_sizes[0] / 2;               // 131072 = 4096 * P
    float* out = (float*)d_out;
    _Float16* ws = (_Float16*)d_ws;              // Wt[2][16][128][8] f16 = 64 KB

    hipLaunchKernelGGL(wt_convert, dim3(256), dim3(64), 0, stream, W1, W2, ws);

    hipLaunchKernelGGL(pinn_hess_mfma, dim3(N / P), dim3(NT), 0, stream,
                       X, W0, b0, ws, b1, b2, W3, out, N);
}